// Round 13
// baseline (505.890 us; speedup 1.0000x reference)
//
#include <hip/hip_runtime.h>
#include <hip/hip_bf16.h>

typedef __hip_bfloat16 bf16;
typedef __attribute__((ext_vector_type(8))) short s8v;   // 8 bf16 = 16 B
typedef __attribute__((ext_vector_type(4))) short s4v;   // 4 bf16 = 8 B
typedef __attribute__((ext_vector_type(4))) float f4v;   // MFMA C/D frag

#define B_  4
#define L_  2048
#define D_  2048
#define H_  16
#define HD_ 128

// scale(1/sqrt(128)) * log2(e): folds attention scale AND exp->exp2 into Q
#define QSCALE 0.12751745f

// ---------------------------------------------------------------------------
// dtype helpers (m: 0 = bf16, 1 = fp32) — only used on cold paths now.
// ---------------------------------------------------------------------------
__device__ __forceinline__ float ldm(const void* p, size_t i, int m) {
    return m ? ((const float*)p)[i]
             : __bfloat162float(((const bf16*)p)[i]);
}
__device__ __forceinline__ void stm(void* p, size_t i, int m, float v) {
    if (m) ((float*)p)[i] = v;
    else   ((bf16*)p)[i] = __float2bfloat16(v);
}

__device__ __forceinline__ void glds16(const bf16* g, bf16* l) {
    __builtin_amdgcn_global_load_lds(
        (const __attribute__((address_space(1))) void*)g,
        (__attribute__((address_space(3))) void*)l, 16, 0, 0);
}

// ---------------------------------------------------------------------------
// Convert (fp32->bf16) or copy (bf16->bf16), 8 elements/thread.
// ---------------------------------------------------------------------------
__global__ __launch_bounds__(256) void cvt_kernel(
    const void* __restrict__ src, bf16* __restrict__ dst, int n8, int m)
{
    int i = blockIdx.x * 256 + threadIdx.x;
    if (i >= n8) return;
    if (m) {
        const f4v* p = (const f4v*)src + (size_t)i * 2;
        f4v a = p[0], b = p[1];
        bf16 t[8];
        #pragma unroll
        for (int e = 0; e < 4; e++) {
            t[e]     = __float2bfloat16(a[e]);
            t[4 + e] = __float2bfloat16(b[e]);
        }
        ((s8v*)dst)[i] = *(s8v*)&t[0];
    } else {
        ((s8v*)dst)[i] = ((const s8v*)src)[i];
    }
}

// ---------------------------------------------------------------------------
// 128x128 / BK=32 MFMA GEMM (m97 structure) — used for SKINNY N (kv GEMM):
// at N=256 it gives 128 WGs vs the 256-tile kernel's 32 (grid occupancy
// beats per-tile efficiency for skinny shapes — round-7 lesson).
// ---------------------------------------------------------------------------
__global__ __launch_bounds__(256) void gemm_glds_kernel(
    const bf16* __restrict__ A, const bf16* __restrict__ Bw,
    void* __restrict__ C, size_t cOff, int cm, int N, int K)
{
    __shared__ bf16 a_lds[128 * 32];   // linear: glds dest must be unpadded
    __shared__ bf16 b_lds[128 * 32];
    const int t = threadIdx.x;

    // XCD-aware swizzle (nwg % 8 == 0 for all our launches)
    const int nbx = gridDim.x;
    const int id  = blockIdx.y * nbx + blockIdx.x;
    const int cpx = (nbx * (int)gridDim.y) >> 3;
    const int swz = (id & 7) * cpx + (id >> 3);
    const int n0  = (swz % nbx) * 128;
    const int m0  = (swz / nbx) * 128;

    const int w  = t >> 6, ln = t & 63;
    const int wr = w >> 1, wc = w & 1;
    const int fr = ln & 15, kg = ln >> 4;

    const int srow = w * 32 + (ln >> 2);
    const int scol = (ln & 3) * 8;
    const bf16* ga = A  + (size_t)(m0 + srow) * K + scol;
    const bf16* gb = Bw + (size_t)(n0 + srow) * K + scol;
    bf16* la = &a_lds[w * 1024];
    bf16* lb = &b_lds[w * 1024];

    f4v acc[4][4];
    #pragma unroll
    for (int i = 0; i < 4; i++)
        #pragma unroll
        for (int j = 0; j < 4; j++)
            #pragma unroll
            for (int r = 0; r < 4; r++) acc[i][j][r] = 0.f;

    for (int k0 = 0; k0 < K; k0 += 32) {
        __syncthreads();
        glds16(ga + k0,          la);
        glds16(ga + k0 + 16 * K, la + 512);
        glds16(gb + k0,          lb);
        glds16(gb + k0 + 16 * K, lb + 512);
        __syncthreads();

        s8v af[4], bfv[4];
        #pragma unroll
        for (int i = 0; i < 4; i++)
            af[i] = *(const s8v*)&a_lds[(wr * 64 + i * 16 + fr) * 32 + kg * 8];
        #pragma unroll
        for (int j = 0; j < 4; j++)
            bfv[j] = *(const s8v*)&b_lds[(wc * 64 + j * 16 + fr) * 32 + kg * 8];
        #pragma unroll
        for (int i = 0; i < 4; i++)
            #pragma unroll
            for (int j = 0; j < 4; j++)
                acc[i][j] = __builtin_amdgcn_mfma_f32_16x16x32_bf16(
                    af[i], bfv[j], acc[i][j], 0, 0, 0);
    }

    #pragma unroll
    for (int i = 0; i < 4; i++)
        #pragma unroll
        for (int j = 0; j < 4; j++)
            #pragma unroll
            for (int r = 0; r < 4; r++) {
                int row = m0 + wr * 64 + i * 16 + kg * 4 + r;
                int col = n0 + wc * 64 + j * 16 + fr;
                stm(C, cOff + (size_t)row * N + col, cm, acc[i][j][r]);
            }
}

// ---------------------------------------------------------------------------
// 256x256 / BK=64 GEMM, 4-phase K-half pipeline (round-12 verified).
// 8 waves, 512 threads, 128 KiB LDS as [dbuf][khalf][256x32] DMA units.
// 32-col rows give bank-balanced b128 reads (R*16 parity spread = 8/bank,
// the hardware minimum) — no swizzle needed.
// ---------------------------------------------------------------------------
__device__ __forceinline__ void stage_unit(
    const bf16* __restrict__ G, int row0, int k0, int K,
    bf16* lds, int w, int ln)
{
    #pragma unroll
    for (int u = 0; u < 2; u++) {
        int blk = u * 8 + w;                 // 16 chunks of 1 KiB
        int r   = blk * 16 + (ln >> 2);      // 0..255
        int ck  = (ln & 3) * 8;              // 0..24
        glds16(G + (size_t)(row0 + r) * K + k0 + ck, lds + blk * 512);
    }
}

__global__ __launch_bounds__(512, 2) void gemm256_kernel(
    const bf16* __restrict__ A, const bf16* __restrict__ Bw,
    void* __restrict__ C, size_t cOff, int cm, int N, int K)
{
    __shared__ __align__(16) bf16 a_lds[2][2][256 * 32];   // [dbuf][khalf]
    __shared__ __align__(16) bf16 b_lds[2][2][256 * 32];
    const int t = threadIdx.x;

    // XCD-aware swizzle (nwg % 8 == 0 for all our launches)
    const int nbx = gridDim.x;
    const int id  = blockIdx.y * nbx + blockIdx.x;
    const int cpx = (nbx * (int)gridDim.y) >> 3;
    const int swz = (id & 7) * cpx + (id >> 3);
    const int n0  = (swz % nbx) * 256;
    const int m0  = (swz / nbx) * 256;

    const int w  = t >> 6, ln = t & 63;
    const int wr = w >> 2, wc = w & 3;          // 2 x 4 wave grid
    const int fr = ln & 15, kg = ln >> 4;

    f4v acc[8][4];
    #pragma unroll
    for (int i = 0; i < 8; i++)
        #pragma unroll
        for (int j = 0; j < 4; j++)
            #pragma unroll
            for (int r = 0; r < 4; r++) acc[i][j][r] = 0.f;

    const int NT = K >> 6;                       // K-tiles of 64

    // prologue: 6 units in exact FIFO order (12 loads/thread)
    stage_unit(A,  m0, 0,  K, &a_lds[0][0][0], w, ln);   // a0(0)
    stage_unit(Bw, n0, 0,  K, &b_lds[0][0][0], w, ln);   // b0(0)
    stage_unit(A,  m0, 32, K, &a_lds[0][1][0], w, ln);   // a1(0)
    stage_unit(Bw, n0, 32, K, &b_lds[0][1][0], w, ln);   // b1(0)
    if (NT > 1) {
        stage_unit(A,  m0, 64, K, &a_lds[1][0][0], w, ln); // a0(1)
        stage_unit(Bw, n0, 64, K, &b_lds[1][0][0], w, ln); // b0(1)
    }

    for (int kt = 0; kt < NT; ++kt) {
        const int c = kt & 1, nb = c ^ 1;
        // ---- W1: a0(kt), b0(kt) ready ----
        if (kt + 1 < NT) asm volatile("s_waitcnt vmcnt(8)" ::: "memory");
        else             asm volatile("s_waitcnt vmcnt(4)" ::: "memory");
        __builtin_amdgcn_s_barrier();

        // ---- P1: stage a1(kt+1); compute kst0 x j{0,1} ----
        if (kt + 1 < NT)
            stage_unit(A, m0, (kt + 1) * 64 + 32, K, &a_lds[nb][1][0], w, ln);
        {
            s8v af[8], bfv[4];
            #pragma unroll
            for (int i = 0; i < 8; i++)
                af[i] = *(const s8v*)&a_lds[c][0][(wr * 128 + i * 16 + fr) * 32 + kg * 8];
            #pragma unroll
            for (int j = 0; j < 2; j++)
                bfv[j] = *(const s8v*)&b_lds[c][0][(wc * 64 + j * 16 + fr) * 32 + kg * 8];
            asm volatile("s_waitcnt lgkmcnt(0)" ::: "memory");
            __builtin_amdgcn_s_setprio(1);
            #pragma unroll
            for (int i = 0; i < 8; i++)
                #pragma unroll
                for (int j = 0; j < 2; j++)
                    acc[i][j] = __builtin_amdgcn_mfma_f32_16x16x32_bf16(
                        af[i], bfv[j], acc[i][j], 0, 0, 0);
            __builtin_amdgcn_s_setprio(0);

            // ---- P2: stage b1(kt+1); compute kst0 x j{2,3} ----
            if (kt + 1 < NT)
                stage_unit(Bw, n0, (kt + 1) * 64 + 32, K, &b_lds[nb][1][0], w, ln);
            #pragma unroll
            for (int j = 2; j < 4; j++)
                bfv[j] = *(const s8v*)&b_lds[c][0][(wc * 64 + j * 16 + fr) * 32 + kg * 8];
            asm volatile("s_waitcnt lgkmcnt(0)" ::: "memory");
            __builtin_amdgcn_s_setprio(1);
            #pragma unroll
            for (int i = 0; i < 8; i++)
                #pragma unroll
                for (int j = 2; j < 4; j++)
                    acc[i][j] = __builtin_amdgcn_mfma_f32_16x16x32_bf16(
                        af[i], bfv[j], acc[i][j], 0, 0, 0);
            __builtin_amdgcn_s_setprio(0);
        }

        // ---- W2: a1(kt), b1(kt) ready ----
        if (kt + 1 < NT) asm volatile("s_waitcnt vmcnt(8)" ::: "memory");
        else             asm volatile("s_waitcnt vmcnt(0)" ::: "memory");
        __builtin_amdgcn_s_barrier();

        // ---- P3: stage a0(kt+2); compute kst1 x j{0,1} ----
        if (kt + 2 < NT)
            stage_unit(A, m0, (kt + 2) * 64, K, &a_lds[c][0][0], w, ln);
        {
            s8v af[8], bfv[4];
            #pragma unroll
            for (int i = 0; i < 8; i++)
                af[i] = *(const s8v*)&a_lds[c][1][(wr * 128 + i * 16 + fr) * 32 + kg * 8];
            #pragma unroll
            for (int j = 0; j < 2; j++)
                bfv[j] = *(const s8v*)&b_lds[c][1][(wc * 64 + j * 16 + fr) * 32 + kg * 8];
            asm volatile("s_waitcnt lgkmcnt(0)" ::: "memory");
            __builtin_amdgcn_s_setprio(1);
            #pragma unroll
            for (int i = 0; i < 8; i++)
                #pragma unroll
                for (int j = 0; j < 2; j++)
                    acc[i][j] = __builtin_amdgcn_mfma_f32_16x16x32_bf16(
                        af[i], bfv[j], acc[i][j], 0, 0, 0);
            __builtin_amdgcn_s_setprio(0);

            // ---- P4: stage b0(kt+2); compute kst1 x j{2,3} ----
            if (kt + 2 < NT)
                stage_unit(Bw, n0, (kt + 2) * 64, K, &b_lds[c][0][0], w, ln);
            #pragma unroll
            for (int j = 2; j < 4; j++)
                bfv[j] = *(const s8v*)&b_lds[c][1][(wc * 64 + j * 16 + fr) * 32 + kg * 8];
            asm volatile("s_waitcnt lgkmcnt(0)" ::: "memory");
            __builtin_amdgcn_s_setprio(1);
            #pragma unroll
            for (int i = 0; i < 8; i++)
                #pragma unroll
                for (int j = 2; j < 4; j++)
                    acc[i][j] = __builtin_amdgcn_mfma_f32_16x16x32_bf16(
                        af[i], bfv[j], acc[i][j], 0, 0, 0);
            __builtin_amdgcn_s_setprio(0);
        }
    }

    #pragma unroll
    for (int i = 0; i < 8; i++)
        #pragma unroll
        for (int j = 0; j < 4; j++)
            #pragma unroll
            for (int r = 0; r < 4; r++) {
                int row = m0 + wr * 128 + i * 16 + kg * 4 + r;
                int col = n0 + wc * 64 + j * 16 + fr;
                stm(C, cOff + (size_t)row * N + col, cm, acc[i][j][r]);
            }
}

// ---------------------------------------------------------------------------
// rotary + RMS-norm (kv path only now), pure-bf16 in-place; optional bf16
// copy (kout) and ext-dtype copy (out2) for the new_k output.
// ---------------------------------------------------------------------------
__global__ __launch_bounds__(256) void rot_rms_kernel(
    bf16* __restrict__ p, int stride, int ldiv, float oscale,
    const void* __restrict__ cosb, const void* __restrict__ sinb, int em,
    bf16* __restrict__ kout, void* __restrict__ out2, int om)
{
    const int row  = blockIdx.x * 4 + (threadIdx.x >> 6);
    const int lane = threadIdx.x & 63;
    const int l    = (row / ldiv) % L_;
    bf16* pr = p + (size_t)row * stride;

    float x1 = __bfloat162float(pr[lane]);
    float x2 = __bfloat162float(pr[lane + 64]);
    float c  = ldm(cosb, (size_t)l * 64 + lane, em);
    float s  = ldm(sinb, (size_t)l * 64 + lane, em);
    float y1 =  x1 * c + x2 * s;
    float y2 = -x1 * s + x2 * c;

    float sq = y1 * y1 + y2 * y2;
    #pragma unroll
    for (int off = 32; off > 0; off >>= 1) sq += __shfl_xor(sq, off);
    float rinv = rsqrtf(sq * (1.0f / 128.0f) + 1.1920929e-07f);
    y1 *= rinv; y2 *= rinv;

    pr[lane]      = __float2bfloat16(y1 * oscale);
    pr[lane + 64] = __float2bfloat16(y2 * oscale);
    if (kout) {
        kout[(size_t)row * HD_ + lane]      = __float2bfloat16(y1);
        kout[(size_t)row * HD_ + lane + 64] = __float2bfloat16(y2);
    }
    if (out2) {
        stm(out2, (size_t)row * HD_ + lane,      om, y1);
        stm(out2, (size_t)row * HD_ + lane + 64, om, y2);
    }
}

// ---------------------------------------------------------------------------
// V transpose: v (bf16, strided rows) -> vt [B][HD][L] bf16, plus new_v copy
// to out-dtype buffer.
// ---------------------------------------------------------------------------
__global__ __launch_bounds__(256) void transpose_v_kernel(
    const bf16* __restrict__ v, int vstride, int vcol0,
    bf16* __restrict__ vt, void* __restrict__ vout, int om)
{
    const int l0 = blockIdx.x * 32, c0 = blockIdx.y * 32, b = blockIdx.z;
    __shared__ bf16 tile[32][36];
    const int t = threadIdx.x;
    {
        int r = t >> 3, c4 = (t & 7) * 4;
        const bf16* src = v + (size_t)(b * L_ + l0 + r) * vstride + vcol0 + c0 + c4;
        s4v sv = *(const s4v*)src;
        *(s4v*)&tile[r][c4] = sv;
        size_t oidx = (size_t)(b * L_ + l0 + r) * HD_ + c0 + c4;
        if (om) {
            f4v f;
            #pragma unroll
            for (int e = 0; e < 4; e++) f[e] = __bfloat162float(((bf16*)&sv)[e]);
            *(f4v*)((float*)vout + oidx) = f;
        } else {
            *(s4v*)((bf16*)vout + oidx) = sv;
        }
    }
    __syncthreads();
    {
        int c = t >> 3, r4 = (t & 7) * 4;
        bf16 tmp[4];
        #pragma unroll
        for (int e = 0; e < 4; e++) tmp[e] = tile[r4 + e][c];
        *(s4v*)&vt[(size_t)(b * HD_ + c0 + c) * L_ + l0 + r4] = *(s4v*)&tmp[0];
    }
}

// ---------------------------------------------------------------------------
// MFMA causal flash attention — round-11/12 structure + round-13 change:
// rot_rms(q) FUSED into the Q-fragment load (drops the 64 MB rot_rms-q
// dispatch). Exactness by fragment layout: rotary pairs (d, d+64) are
// lane-local (kst vs kst+2 of the same lane); RMS row-sum = reduce over
// the 4 kg lane-groups = shfl_xor(16)+shfl_xor(32) (lane = kg*16+fr).
// QSCALE*log2e folded into rinv. One bf16 round-trip removed from q.
// ---------------------------------------------------------------------------
__global__ __launch_bounds__(256, 2) void attn_kernel(
    const bf16* __restrict__ q,
    const bf16* __restrict__ kbuf,
    const bf16* __restrict__ vt,
    bf16* __restrict__ o,
    const void* __restrict__ cosb, const void* __restrict__ sinb, int em)
{
    const int bx = blockIdx.x;
    const int h  = blockIdx.y, b = blockIdx.z;
    const int t  = threadIdx.x, w = t >> 6, ln = t & 63;
    const int fr = ln & 15, kg = ln >> 4;

    __shared__ bf16 k_lds[64][132];    // K tile  [key][hd]   (+4 pad)
    __shared__ bf16 vt_lds[128][68];   // V^T tile [hd][key]  (+4 pad)
    __shared__ bf16 p_lds[128][68];    // P tile  [qrow][key] (+4 pad)

    // staging geometry: K 64x128 (4 s8v/thread), V^T 128x64 (4 s8v/thread)
    const int rK = t >> 2, cK = (t & 3) * 32;
    const int rV = t >> 1, cV = (t & 1) * 32;

    #pragma unroll 1
    for (int half = 0; half < 2; half++) {
        const int l0 = half ? (L_ - 128 - bx * 128) : bx * 128;

        // ---- Q fragments: raw load + fused rotary + RMS-norm + QSCALE ----
        s8v qf[2][4];
        #pragma unroll
        for (int s = 0; s < 2; s++) {
            const int l = l0 + w * 32 + s * 16 + fr;
            size_t base = (size_t)(b * L_ + l) * D_ + h * HD_ + kg * 8;
            #pragma unroll
            for (int kst = 0; kst < 4; kst++)
                qf[s][kst] = *(const s8v*)(q + base + kst * 32);

            float y[4][8];
            float sq = 0.f;
            #pragma unroll
            for (int k = 0; k < 2; k++)
                #pragma unroll
                for (int e = 0; e < 8; e++) {
                    int j = k * 32 + kg * 8 + e;           // rotary index 0..63
                    float x1 = __bfloat162float(((bf16*)&qf[s][k])[e]);
                    float x2 = __bfloat162float(((bf16*)&qf[s][k + 2])[e]);
                    float c  = ldm(cosb, (size_t)l * 64 + j, em);
                    float sn = ldm(sinb, (size_t)l * 64 + j, em);
                    float y1 =  x1 * c + x2 * sn;
                    float y2 = -x1 * sn + x2 * c;
                    y[k][e] = y1; y[k + 2][e] = y2;
                    sq += y1 * y1 + y2 * y2;
                }
            sq += __shfl_xor(sq, 16);   // reduce over kg groups (lane=kg*16+fr)
            sq += __shfl_xor(sq, 32);
            float rinv = rsqrtf(sq * (1.0f / 128.0f) + 1.1920929e-07f) * QSCALE;
            #pragma unroll
            for (int kst = 0; kst < 4; kst++)
                #pragma unroll
                for (int e = 0; e < 8; e++)
                    ((bf16*)&qf[s][kst])[e] = __float2bfloat16(y[kst][e] * rinv);
        }

        float m_i[2] = {-3.0e38f, -3.0e38f};
        float l_i[2] = {0.f, 0.f};
        f4v o_acc[8][2];
        #pragma unroll
        for (int mt = 0; mt < 8; mt++)
            #pragma unroll
            for (int s = 0; s < 2; s++)
                #pragma unroll
                for (int r = 0; r < 4; r++) o_acc[mt][s][r] = 0.f;

        const int qmax_w = l0 + w * 32 + 31;   // wave's max q-row
        const int kend   = l0 + 128;

        for (int kb = 0; kb < kend; kb += 64) {
            // hoisted staging loads: registers only until after the sync
            s8v kr[4], vr[4];
            {
                const s8v* ks = (const s8v*)(kbuf + (size_t)(b * L_ + kb + rK) * HD_ + cK);
                const s8v* vs = (const s8v*)(vt + (size_t)(b * HD_ + rV) * L_ + kb + cV);
                #pragma unroll
                for (int u = 0; u < 4; u++) { kr[u] = ks[u]; vr[u] = vs[u]; }
            }
            __syncthreads();   // previous tile fully consumed
            #pragma unroll
            for (int u = 0; u < 4; u++) {
                *(s8v*)&k_lds[rK][cK + u * 8]  = kr[u];
                *(s8v*)&vt_lds[rV][cV + u * 8] = vr[u];
            }
            __syncthreads();   // tile ready

            if (kb <= qmax_w) {
                // ---- S^T = K · Q^T (log2 domain via Q pre-scale) ----
                f4v sacc[4][2];
                #pragma unroll
                for (int jm = 0; jm < 4; jm++)
                    #pragma unroll
                    for (int s = 0; s < 2; s++)
                        #pragma unroll
                        for (int r = 0; r < 4; r++) sacc[jm][s][r] = 0.f;

                __builtin_amdgcn_s_setprio(1);
                #pragma unroll
                for (int kst = 0; kst < 4; kst++) {
                    #pragma unroll
                    for (int jm = 0; jm < 4; jm++) {
                        s8v af = *(const s8v*)&k_lds[jm * 16 + fr][kst * 32 + kg * 8];
                        #pragma unroll
                        for (int s = 0; s < 2; s++)
                            sacc[jm][s] = __builtin_amdgcn_mfma_f32_16x16x32_bf16(
                                af, qf[s][kst], sacc[jm][s], 0, 0, 0);
                    }
                }
                __builtin_amdgcn_s_setprio(0);

                // ---- online softmax per strip ----
                #pragma unroll
                for (int s = 0; s < 2; s++) {
                    const int qrow = l0 + w * 32 + s * 16 + fr;
                    float sv[4][4];
                    if (kb + 63 > l0 + w * 32 + s * 16) {   // diagonal tile: mask
                        #pragma unroll
                        for (int jm = 0; jm < 4; jm++)
                            #pragma unroll
                            for (int r = 0; r < 4; r++) {
                                int key = kb + jm * 16 + kg * 4 + r;
                                sv[jm][r] = (key <= qrow) ? sacc[jm][s][r] : -3.0e38f;
                            }
                    } else {                                 // interior tile
                        #pragma unroll
                        for (int jm = 0; jm < 4; jm++)
                            #pragma unroll
                            for (int r = 0; r < 4; r++) sv[jm][r] = sacc[jm][s][r];
                    }
                    float mj[4];
                    #pragma unroll
                    for (int jm = 0; jm < 4; jm++)
                        mj[jm] = fmaxf(fmaxf(sv[jm][0], sv[jm][1]),
                                       fmaxf(sv[jm][2], sv[jm][3]));
                    float mx = fmaxf(fmaxf(mj[0], mj[1]), fmaxf(mj[2], mj[3]));
                    mx = fmaxf(mx, __shfl_xor(mx, 16));
                    mx = fmaxf(mx, __shfl_xor(mx, 32));

                    // T13 defer-max: only rescale when the max actually grew
                    float mn = m_i[s];
                    if (!__all(mx - mn <= 8.0f)) {
                        float mnew  = fmaxf(mn, mx);
                        float alpha = exp2f(mn - mnew);
                        m_i[s] = mnew;
                        l_i[s] *= alpha;
                        #pragma unroll
                        for (int mt = 0; mt < 8; mt++)
                            #pragma unroll
                            for (int r = 0; r < 4; r++) o_acc[mt][s][r] *= alpha;
                        mn = mnew;
                    }

                    float rs0 = 0.f, rs1 = 0.f;
                    #pragma unroll
                    for (int jm = 0; jm < 4; jm++) {
                        float p0 = exp2f(sv[jm][0] - mn);
                        float p1 = exp2f(sv[jm][1] - mn);
                        float p2 = exp2f(sv[jm][2] - mn);
                        float p3 = exp2f(sv[jm][3] - mn);
                        rs0 += p0 + p2;
                        rs1 += p1 + p3;
                        bf16 pb[4];
                        pb[0] = __float2bfloat16(p0);
                        pb[1] = __float2bfloat16(p1);
                        pb[2] = __float2bfloat16(p2);
                        pb[3] = __float2bfloat16(p3);
                        *(s4v*)&p_lds[w * 32 + s * 16 + fr][jm * 16 + kg * 4] =
                            *(s4v*)&pb[0];
                    }
                    float rsum = rs0 + rs1;
                    rsum += __shfl_xor(rsum, 16);
                    rsum += __shfl_xor(rsum, 32);
                    l_i[s] += rsum;
                }

                // ---- O^T += V^T · P^T ----
                __builtin_amdgcn_s_setprio(1);
                #pragma unroll
                for (int ks2 = 0; ks2 < 2; ks2++) {
                    s8v pf[2];
                    #pragma unroll
                    for (int s = 0; s < 2; s++)
                        pf[s] = *(const s8v*)&p_lds[w * 32 + s * 16 + fr][ks2 * 32 + kg * 8];
                    #pragma unroll
                    for (int mt = 0; mt < 8; mt++) {
                        s8v vf = *(const s8v*)&vt_lds[mt * 16 + fr][ks2 * 32 + kg * 8];
                        #pragma unroll
                        for (int s = 0; s < 2; s++)
                            o_acc[mt][s] = __builtin_amdgcn_mfma_f32_16x16x32_bf16(
                                vf, pf[s], o_acc[mt][s], 0, 0, 0);
                    }
                }
                __builtin_amdgcn_s_setprio(0);
            }
        }

        // ---- epilogue: O^T C-layout -> 4 consecutive hd per lane -> b64 stores
        #pragma unroll
        for (int s = 0; s < 2; s++) {
            float rl = 1.f / l_i[s];
            size_t base = (size_t)(b * L_ + l0 + w * 32 + s * 16 + fr) * D_
                          + h * HD_ + kg * 4;
            #pragma unroll
            for (int mt = 0; mt < 8; mt++) {
                bf16 ob[4];
                #pragma unroll
                for (int r = 0; r < 4; r++)
                    ob[r] = __float2bfloat16(o_acc[mt][s][r] * rl);
                *(s4v*)(o + base + mt * 16) = *(s4v*)&ob[0];
            }
        }
    }
}

// ---------------------------------------------------------------------------
extern "C" void kernel_launch(void* const* d_in, const int* in_sizes, int n_in,
                              void* d_out, int out_size, void* d_ws, size_t ws_size,
                              hipStream_t stream)
{
    const void* x    = d_in[0];
    const void* cosb = d_in[1];
    const void* sinb = d_in[2];
    const void* Wq   = d_in[3];
    const void* Wk   = d_in[4];
    const void* Wv   = d_in[5];
    const void* Wo   = d_in[6];

    const size_t NX   = (size_t)B_ * L_ * D_;     // 16,777,216
    const size_t NW   = (size_t)D_ * D_;          //  4,194,304
    const size_t NWK  = (size_t)HD_ * D_;         //    262,144
    const size_t NKV  = (size_t)B_ * L_ * HD_;    //  1,048,576
    const size_t NOUT = NX + 2 * NKV;             // 18,874,368

    const int xm  = (in_sizes[0] == (int)(NX * 2))  ? 0 : 1;
    const int em  = (in_sizes[1] == (int)((size_t)L_ * 64 * 2)) ? 0 : 1;
    const int wm  = (in_sizes[3] == (int)(NW * 2))  ? 0 : 1;
    const int wkm = (in_sizes[4] == (int)(NWK * 2)) ? 0 : 1;
    const int om  = (out_size    == (int)(NOUT * 2)) ? 0 : 1;

    bf16* qbuf  = (bf16*)d_ws;
    bf16* kvbuf = qbuf  + NX;
    bf16* kbuf  = kvbuf + (size_t)B_ * L_ * 256;
    bf16* vtbuf = kbuf  + NKV;
    bf16* wkvb  = vtbuf + NKV;
    bf16* wwb   = kvbuf;   // 8 MiB scratch spanning kvbuf+kbuf+vtbuf

    const bf16* xb;
    if (xm) {
        cvt_kernel<<<(int)(NX / 8 / 256), 256, 0, stream>>>(x, (bf16*)d_out, (int)(NX / 8), 1);
        xb = (const bf16*)d_out;
    } else {
        xb = (const bf16*)x;
    }

    const bf16* wq;
    if (wm) {
        cvt_kernel<<<(int)(NW / 8 / 256), 256, 0, stream>>>(Wq, wwb, (int)(NW / 8), 1);
        wq = wwb;
    } else {
        wq = (const bf16*)Wq;
    }
    cvt_kernel<<<(int)(NWK / 8 / 256), 256, 0, stream>>>(Wk, wkvb,       (int)(NWK / 8), wkm);
    cvt_kernel<<<(int)(NWK / 8 / 256), 256, 0, stream>>>(Wv, wkvb + NWK, (int)(NWK / 8), wkm);

    // q = x @ Wq^T  (bf16 out into qbuf) — raw; rot+rms fused into attn
    gemm256_kernel<<<dim3(D_ / 256, (B_ * L_) / 256), 512, 0, stream>>>(
        xb, wq, qbuf, 0, 0, D_, D_);
    // [k|v] = x @ [Wk;Wv]^T  (bf16 out, N=256) — skinny N: 128-tile kernel
    gemm_glds_kernel<<<dim3(256 / 128, (B_ * L_) / 128), 256, 0, stream>>>(
        xb, wkvb, kvbuf, 0, 0, 256, D_);

    // k path: rot+rms in place + bf16 copy (kbuf) + new_k output copy
    char* d_out_b = (char*)d_out;
    void* kout2 = d_out_b + NX * (om ? 4 : 2);
    rot_rms_kernel<<<(B_ * L_) / 4, 256, 0, stream>>>(
        kvbuf, 256, 1, 1.0f, cosb, sinb, em, kbuf, kout2, om);

    void* vout2 = d_out_b + (NX + NKV) * (om ? 4 : 2);
    transpose_v_kernel<<<dim3(L_ / 32, HD_ / 32, B_), 256, 0, stream>>>(
        kvbuf, 256, 128, vtbuf, vout2, om);

    // attention: equal-work paired blocks (bx + mirror), grid 512;
    // q rotary+rms fused into the Q-fragment load
    attn_kernel<<<dim3(L_ / 256, H_, B_), 256, 0, stream>>>(
        qbuf, kbuf, vtbuf, qbuf, cosb, sinb, em);

    const bf16* wo;
    if (wm) {
        cvt_kernel<<<(int)(NW / 8 / 256), 256, 0, stream>>>(Wo, wwb, (int)(NW / 8), 1);
        wo = wwb;
    } else {
        wo = (const bf16*)Wo;
    }
    // out = attn @ Wo^T  (out-dtype store into d_out) — big N: 4-phase kernel
    gemm256_kernel<<<dim3(D_ / 256, (B_ * L_) / 256), 512, 0, stream>>>(
        qbuf, wo, d_out, 0, om, D_, D_);
}

// Round 14
// 485.499 us; speedup vs baseline: 1.0420x; 1.0420x over previous
//
#include <hip/hip_runtime.h>
#include <hip/hip_bf16.h>

typedef __hip_bfloat16 bf16;
typedef __attribute__((ext_vector_type(8))) short s8v;   // 8 bf16 = 16 B
typedef __attribute__((ext_vector_type(4))) short s4v;   // 4 bf16 = 8 B
typedef __attribute__((ext_vector_type(4))) float f4v;   // MFMA C/D frag

#define B_  4
#define L_  2048
#define D_  2048
#define H_  16
#define HD_ 128

// scale(1/sqrt(128)) * log2(e): folds attention scale AND exp->exp2 into Q
#define QSCALE 0.12751745f

// ---------------------------------------------------------------------------
// dtype helpers (m: 0 = bf16, 1 = fp32) — only used on cold paths now.
// ---------------------------------------------------------------------------
__device__ __forceinline__ float ldm(const void* p, size_t i, int m) {
    return m ? ((const float*)p)[i]
             : __bfloat162float(((const bf16*)p)[i]);
}
__device__ __forceinline__ void stm(void* p, size_t i, int m, float v) {
    if (m) ((float*)p)[i] = v;
    else   ((bf16*)p)[i] = __float2bfloat16(v);
}

// vectorized 8-element load (fp32: 2x f4v, bf16: 1x s8v) — G13: never scalar
__device__ __forceinline__ void ld8(const void* p, size_t off, int m, float* out) {
    if (m) {
        f4v a = *(const f4v*)((const float*)p + off);
        f4v b = *(const f4v*)((const float*)p + off + 4);
        #pragma unroll
        for (int e = 0; e < 4; e++) { out[e] = a[e]; out[4 + e] = b[e]; }
    } else {
        s8v v = *(const s8v*)((const bf16*)p + off);
        #pragma unroll
        for (int e = 0; e < 8; e++) out[e] = __bfloat162float(((bf16*)&v)[e]);
    }
}

__device__ __forceinline__ void glds16(const bf16* g, bf16* l) {
    __builtin_amdgcn_global_load_lds(
        (const __attribute__((address_space(1))) void*)g,
        (__attribute__((address_space(3))) void*)l, 16, 0, 0);
}

// ---------------------------------------------------------------------------
// Convert (fp32->bf16) or copy (bf16->bf16), 8 elements/thread.
// ---------------------------------------------------------------------------
__global__ __launch_bounds__(256) void cvt_kernel(
    const void* __restrict__ src, bf16* __restrict__ dst, int n8, int m)
{
    int i = blockIdx.x * 256 + threadIdx.x;
    if (i >= n8) return;
    if (m) {
        const f4v* p = (const f4v*)src + (size_t)i * 2;
        f4v a = p[0], b = p[1];
        bf16 t[8];
        #pragma unroll
        for (int e = 0; e < 4; e++) {
            t[e]     = __float2bfloat16(a[e]);
            t[4 + e] = __float2bfloat16(b[e]);
        }
        ((s8v*)dst)[i] = *(s8v*)&t[0];
    } else {
        ((s8v*)dst)[i] = ((const s8v*)src)[i];
    }
}

// ---------------------------------------------------------------------------
// 128x128 / BK=32 MFMA GEMM (m97 structure) — used for SKINNY N (kv GEMM):
// at N=256 it gives 128 WGs vs the 256-tile kernel's 32 (grid occupancy
// beats per-tile efficiency for skinny shapes — round-7 lesson).
// ---------------------------------------------------------------------------
__global__ __launch_bounds__(256) void gemm_glds_kernel(
    const bf16* __restrict__ A, const bf16* __restrict__ Bw,
    void* __restrict__ C, size_t cOff, int cm, int N, int K)
{
    __shared__ bf16 a_lds[128 * 32];   // linear: glds dest must be unpadded
    __shared__ bf16 b_lds[128 * 32];
    const int t = threadIdx.x;

    // XCD-aware swizzle (nwg % 8 == 0 for all our launches)
    const int nbx = gridDim.x;
    const int id  = blockIdx.y * nbx + blockIdx.x;
    const int cpx = (nbx * (int)gridDim.y) >> 3;
    const int swz = (id & 7) * cpx + (id >> 3);
    const int n0  = (swz % nbx) * 128;
    const int m0  = (swz / nbx) * 128;

    const int w  = t >> 6, ln = t & 63;
    const int wr = w >> 1, wc = w & 1;
    const int fr = ln & 15, kg = ln >> 4;

    const int srow = w * 32 + (ln >> 2);
    const int scol = (ln & 3) * 8;
    const bf16* ga = A  + (size_t)(m0 + srow) * K + scol;
    const bf16* gb = Bw + (size_t)(n0 + srow) * K + scol;
    bf16* la = &a_lds[w * 1024];
    bf16* lb = &b_lds[w * 1024];

    f4v acc[4][4];
    #pragma unroll
    for (int i = 0; i < 4; i++)
        #pragma unroll
        for (int j = 0; j < 4; j++)
            #pragma unroll
            for (int r = 0; r < 4; r++) acc[i][j][r] = 0.f;

    for (int k0 = 0; k0 < K; k0 += 32) {
        __syncthreads();
        glds16(ga + k0,          la);
        glds16(ga + k0 + 16 * K, la + 512);
        glds16(gb + k0,          lb);
        glds16(gb + k0 + 16 * K, lb + 512);
        __syncthreads();

        s8v af[4], bfv[4];
        #pragma unroll
        for (int i = 0; i < 4; i++)
            af[i] = *(const s8v*)&a_lds[(wr * 64 + i * 16 + fr) * 32 + kg * 8];
        #pragma unroll
        for (int j = 0; j < 4; j++)
            bfv[j] = *(const s8v*)&b_lds[(wc * 64 + j * 16 + fr) * 32 + kg * 8];
        #pragma unroll
        for (int i = 0; i < 4; i++)
            #pragma unroll
            for (int j = 0; j < 4; j++)
                acc[i][j] = __builtin_amdgcn_mfma_f32_16x16x32_bf16(
                    af[i], bfv[j], acc[i][j], 0, 0, 0);
    }

    #pragma unroll
    for (int i = 0; i < 4; i++)
        #pragma unroll
        for (int j = 0; j < 4; j++)
            #pragma unroll
            for (int r = 0; r < 4; r++) {
                int row = m0 + wr * 64 + i * 16 + kg * 4 + r;
                int col = n0 + wc * 64 + j * 16 + fr;
                stm(C, cOff + (size_t)row * N + col, cm, acc[i][j][r]);
            }
}

// ---------------------------------------------------------------------------
// 256x256 / BK=64 GEMM, 4-phase K-half pipeline (round-12 verified).
// ---------------------------------------------------------------------------
__device__ __forceinline__ void stage_unit(
    const bf16* __restrict__ G, int row0, int k0, int K,
    bf16* lds, int w, int ln)
{
    #pragma unroll
    for (int u = 0; u < 2; u++) {
        int blk = u * 8 + w;                 // 16 chunks of 1 KiB
        int r   = blk * 16 + (ln >> 2);      // 0..255
        int ck  = (ln & 3) * 8;              // 0..24
        glds16(G + (size_t)(row0 + r) * K + k0 + ck, lds + blk * 512);
    }
}

__global__ __launch_bounds__(512, 2) void gemm256_kernel(
    const bf16* __restrict__ A, const bf16* __restrict__ Bw,
    void* __restrict__ C, size_t cOff, int cm, int N, int K)
{
    __shared__ __align__(16) bf16 a_lds[2][2][256 * 32];   // [dbuf][khalf]
    __shared__ __align__(16) bf16 b_lds[2][2][256 * 32];
    const int t = threadIdx.x;

    // XCD-aware swizzle (nwg % 8 == 0 for all our launches)
    const int nbx = gridDim.x;
    const int id  = blockIdx.y * nbx + blockIdx.x;
    const int cpx = (nbx * (int)gridDim.y) >> 3;
    const int swz = (id & 7) * cpx + (id >> 3);
    const int n0  = (swz % nbx) * 256;
    const int m0  = (swz / nbx) * 256;

    const int w  = t >> 6, ln = t & 63;
    const int wr = w >> 2, wc = w & 3;          // 2 x 4 wave grid
    const int fr = ln & 15, kg = ln >> 4;

    f4v acc[8][4];
    #pragma unroll
    for (int i = 0; i < 8; i++)
        #pragma unroll
        for (int j = 0; j < 4; j++)
            #pragma unroll
            for (int r = 0; r < 4; r++) acc[i][j][r] = 0.f;

    const int NT = K >> 6;                       // K-tiles of 64

    // prologue: 6 units in exact FIFO order (12 loads/thread)
    stage_unit(A,  m0, 0,  K, &a_lds[0][0][0], w, ln);   // a0(0)
    stage_unit(Bw, n0, 0,  K, &b_lds[0][0][0], w, ln);   // b0(0)
    stage_unit(A,  m0, 32, K, &a_lds[0][1][0], w, ln);   // a1(0)
    stage_unit(Bw, n0, 32, K, &b_lds[0][1][0], w, ln);   // b1(0)
    if (NT > 1) {
        stage_unit(A,  m0, 64, K, &a_lds[1][0][0], w, ln); // a0(1)
        stage_unit(Bw, n0, 64, K, &b_lds[1][0][0], w, ln); // b0(1)
    }

    for (int kt = 0; kt < NT; ++kt) {
        const int c = kt & 1, nb = c ^ 1;
        // ---- W1: a0(kt), b0(kt) ready ----
        if (kt + 1 < NT) asm volatile("s_waitcnt vmcnt(8)" ::: "memory");
        else             asm volatile("s_waitcnt vmcnt(4)" ::: "memory");
        __builtin_amdgcn_s_barrier();

        // ---- P1: stage a1(kt+1); compute kst0 x j{0,1} ----
        if (kt + 1 < NT)
            stage_unit(A, m0, (kt + 1) * 64 + 32, K, &a_lds[nb][1][0], w, ln);
        {
            s8v af[8], bfv[4];
            #pragma unroll
            for (int i = 0; i < 8; i++)
                af[i] = *(const s8v*)&a_lds[c][0][(wr * 128 + i * 16 + fr) * 32 + kg * 8];
            #pragma unroll
            for (int j = 0; j < 2; j++)
                bfv[j] = *(const s8v*)&b_lds[c][0][(wc * 64 + j * 16 + fr) * 32 + kg * 8];
            asm volatile("s_waitcnt lgkmcnt(0)" ::: "memory");
            __builtin_amdgcn_s_setprio(1);
            #pragma unroll
            for (int i = 0; i < 8; i++)
                #pragma unroll
                for (int j = 0; j < 2; j++)
                    acc[i][j] = __builtin_amdgcn_mfma_f32_16x16x32_bf16(
                        af[i], bfv[j], acc[i][j], 0, 0, 0);
            __builtin_amdgcn_s_setprio(0);

            // ---- P2: stage b1(kt+1); compute kst0 x j{2,3} ----
            if (kt + 1 < NT)
                stage_unit(Bw, n0, (kt + 1) * 64 + 32, K, &b_lds[nb][1][0], w, ln);
            #pragma unroll
            for (int j = 2; j < 4; j++)
                bfv[j] = *(const s8v*)&b_lds[c][0][(wc * 64 + j * 16 + fr) * 32 + kg * 8];
            asm volatile("s_waitcnt lgkmcnt(0)" ::: "memory");
            __builtin_amdgcn_s_setprio(1);
            #pragma unroll
            for (int i = 0; i < 8; i++)
                #pragma unroll
                for (int j = 2; j < 4; j++)
                    acc[i][j] = __builtin_amdgcn_mfma_f32_16x16x32_bf16(
                        af[i], bfv[j], acc[i][j], 0, 0, 0);
            __builtin_amdgcn_s_setprio(0);
        }

        // ---- W2: a1(kt), b1(kt) ready ----
        if (kt + 1 < NT) asm volatile("s_waitcnt vmcnt(8)" ::: "memory");
        else             asm volatile("s_waitcnt vmcnt(0)" ::: "memory");
        __builtin_amdgcn_s_barrier();

        // ---- P3: stage a0(kt+2); compute kst1 x j{0,1} ----
        if (kt + 2 < NT)
            stage_unit(A, m0, (kt + 2) * 64, K, &a_lds[c][0][0], w, ln);
        {
            s8v af[8], bfv[4];
            #pragma unroll
            for (int i = 0; i < 8; i++)
                af[i] = *(const s8v*)&a_lds[c][1][(wr * 128 + i * 16 + fr) * 32 + kg * 8];
            #pragma unroll
            for (int j = 0; j < 2; j++)
                bfv[j] = *(const s8v*)&b_lds[c][1][(wc * 64 + j * 16 + fr) * 32 + kg * 8];
            asm volatile("s_waitcnt lgkmcnt(0)" ::: "memory");
            __builtin_amdgcn_s_setprio(1);
            #pragma unroll
            for (int i = 0; i < 8; i++)
                #pragma unroll
                for (int j = 0; j < 2; j++)
                    acc[i][j] = __builtin_amdgcn_mfma_f32_16x16x32_bf16(
                        af[i], bfv[j], acc[i][j], 0, 0, 0);
            __builtin_amdgcn_s_setprio(0);

            // ---- P4: stage b0(kt+2); compute kst1 x j{2,3} ----
            if (kt + 2 < NT)
                stage_unit(Bw, n0, (kt + 2) * 64, K, &b_lds[c][0][0], w, ln);
            #pragma unroll
            for (int j = 2; j < 4; j++)
                bfv[j] = *(const s8v*)&b_lds[c][1][(wc * 64 + j * 16 + fr) * 32 + kg * 8];
            asm volatile("s_waitcnt lgkmcnt(0)" ::: "memory");
            __builtin_amdgcn_s_setprio(1);
            #pragma unroll
            for (int i = 0; i < 8; i++)
                #pragma unroll
                for (int j = 2; j < 4; j++)
                    acc[i][j] = __builtin_amdgcn_mfma_f32_16x16x32_bf16(
                        af[i], bfv[j], acc[i][j], 0, 0, 0);
            __builtin_amdgcn_s_setprio(0);
        }
    }

    #pragma unroll
    for (int i = 0; i < 8; i++)
        #pragma unroll
        for (int j = 0; j < 4; j++)
            #pragma unroll
            for (int r = 0; r < 4; r++) {
                int row = m0 + wr * 128 + i * 16 + kg * 4 + r;
                int col = n0 + wc * 64 + j * 16 + fr;
                stm(C, cOff + (size_t)row * N + col, cm, acc[i][j][r]);
            }
}

// ---------------------------------------------------------------------------
// rotary + RMS-norm (kv path only), pure-bf16 in-place; optional bf16 copy
// (kout) and ext-dtype copy (out2) for the new_k output.
// ---------------------------------------------------------------------------
__global__ __launch_bounds__(256) void rot_rms_kernel(
    bf16* __restrict__ p, int stride, int ldiv, float oscale,
    const void* __restrict__ cosb, const void* __restrict__ sinb, int em,
    bf16* __restrict__ kout, void* __restrict__ out2, int om)
{
    const int row  = blockIdx.x * 4 + (threadIdx.x >> 6);
    const int lane = threadIdx.x & 63;
    const int l    = (row / ldiv) % L_;
    bf16* pr = p + (size_t)row * stride;

    float x1 = __bfloat162float(pr[lane]);
    float x2 = __bfloat162float(pr[lane + 64]);
    float c  = ldm(cosb, (size_t)l * 64 + lane, em);
    float s  = ldm(sinb, (size_t)l * 64 + lane, em);
    float y1 =  x1 * c + x2 * s;
    float y2 = -x1 * s + x2 * c;

    float sq = y1 * y1 + y2 * y2;
    #pragma unroll
    for (int off = 32; off > 0; off >>= 1) sq += __shfl_xor(sq, off);
    float rinv = rsqrtf(sq * (1.0f / 128.0f) + 1.1920929e-07f);
    y1 *= rinv; y2 *= rinv;

    pr[lane]      = __float2bfloat16(y1 * oscale);
    pr[lane + 64] = __float2bfloat16(y2 * oscale);
    if (kout) {
        kout[(size_t)row * HD_ + lane]      = __float2bfloat16(y1);
        kout[(size_t)row * HD_ + lane + 64] = __float2bfloat16(y2);
    }
    if (out2) {
        stm(out2, (size_t)row * HD_ + lane,      om, y1);
        stm(out2, (size_t)row * HD_ + lane + 64, om, y2);
    }
}

// ---------------------------------------------------------------------------
// V transpose: v (bf16, strided rows) -> vt [B][HD][L] bf16, plus new_v copy
// to out-dtype buffer.
// ---------------------------------------------------------------------------
__global__ __launch_bounds__(256) void transpose_v_kernel(
    const bf16* __restrict__ v, int vstride, int vcol0,
    bf16* __restrict__ vt, void* __restrict__ vout, int om)
{
    const int l0 = blockIdx.x * 32, c0 = blockIdx.y * 32, b = blockIdx.z;
    __shared__ bf16 tile[32][36];
    const int t = threadIdx.x;
    {
        int r = t >> 3, c4 = (t & 7) * 4;
        const bf16* src = v + (size_t)(b * L_ + l0 + r) * vstride + vcol0 + c0 + c4;
        s4v sv = *(const s4v*)src;
        *(s4v*)&tile[r][c4] = sv;
        size_t oidx = (size_t)(b * L_ + l0 + r) * HD_ + c0 + c4;
        if (om) {
            f4v f;
            #pragma unroll
            for (int e = 0; e < 4; e++) f[e] = __bfloat162float(((bf16*)&sv)[e]);
            *(f4v*)((float*)vout + oidx) = f;
        } else {
            *(s4v*)((bf16*)vout + oidx) = sv;
        }
    }
    __syncthreads();
    {
        int c = t >> 3, r4 = (t & 7) * 4;
        bf16 tmp[4];
        #pragma unroll
        for (int e = 0; e < 4; e++) tmp[e] = tile[r4 + e][c];
        *(s4v*)&vt[(size_t)(b * HD_ + c0 + c) * L_ + l0 + r4] = *(s4v*)&tmp[0];
    }
}

// ---------------------------------------------------------------------------
// MFMA causal flash attention — round-13 fusion with VECTORIZED cos/sin
// loads (round-13's scalar ldm per element = 128 scalar loads/thread was
// the +20 µs regression; G13 applies to elementwise too). Each lane needs
// two 8-element contiguous segments per strip -> 8 vector loads total.
// ---------------------------------------------------------------------------
__global__ __launch_bounds__(256, 2) void attn_kernel(
    const bf16* __restrict__ q,
    const bf16* __restrict__ kbuf,
    const bf16* __restrict__ vt,
    bf16* __restrict__ o,
    const void* __restrict__ cosb, const void* __restrict__ sinb, int em)
{
    const int bx = blockIdx.x;
    const int h  = blockIdx.y, b = blockIdx.z;
    const int t  = threadIdx.x, w = t >> 6, ln = t & 63;
    const int fr = ln & 15, kg = ln >> 4;

    __shared__ bf16 k_lds[64][132];    // K tile  [key][hd]   (+4 pad)
    __shared__ bf16 vt_lds[128][68];   // V^T tile [hd][key]  (+4 pad)
    __shared__ bf16 p_lds[128][68];    // P tile  [qrow][key] (+4 pad)

    // staging geometry: K 64x128 (4 s8v/thread), V^T 128x64 (4 s8v/thread)
    const int rK = t >> 2, cK = (t & 3) * 32;
    const int rV = t >> 1, cV = (t & 1) * 32;

    #pragma unroll 1
    for (int half = 0; half < 2; half++) {
        const int l0 = half ? (L_ - 128 - bx * 128) : bx * 128;

        // ---- Q fragments: raw load + fused rotary + RMS-norm + QSCALE ----
        s8v qf[2][4];
        #pragma unroll
        for (int s = 0; s < 2; s++) {
            const int l = l0 + w * 32 + s * 16 + fr;
            size_t base = (size_t)(b * L_ + l) * D_ + h * HD_ + kg * 8;
            #pragma unroll
            for (int kst = 0; kst < 4; kst++)
                qf[s][kst] = *(const s8v*)(q + base + kst * 32);

            float y[4][8];
            float sq = 0.f;
            #pragma unroll
            for (int k = 0; k < 2; k++) {
                float cs[8], sn[8];
                ld8(cosb, (size_t)l * 64 + k * 32 + kg * 8, em, cs);
                ld8(sinb, (size_t)l * 64 + k * 32 + kg * 8, em, sn);
                #pragma unroll
                for (int e = 0; e < 8; e++) {
                    float x1 = __bfloat162float(((bf16*)&qf[s][k])[e]);
                    float x2 = __bfloat162float(((bf16*)&qf[s][k + 2])[e]);
                    float y1 =  x1 * cs[e] + x2 * sn[e];
                    float y2 = -x1 * sn[e] + x2 * cs[e];
                    y[k][e] = y1; y[k + 2][e] = y2;
                    sq += y1 * y1 + y2 * y2;
                }
            }
            sq += __shfl_xor(sq, 16);   // reduce over kg groups (lane=kg*16+fr)
            sq += __shfl_xor(sq, 32);
            float rinv = rsqrtf(sq * (1.0f / 128.0f) + 1.1920929e-07f) * QSCALE;
            #pragma unroll
            for (int kst = 0; kst < 4; kst++)
                #pragma unroll
                for (int e = 0; e < 8; e++)
                    ((bf16*)&qf[s][kst])[e] = __float2bfloat16(y[kst][e] * rinv);
        }

        float m_i[2] = {-3.0e38f, -3.0e38f};
        float l_i[2] = {0.f, 0.f};
        f4v o_acc[8][2];
        #pragma unroll
        for (int mt = 0; mt < 8; mt++)
            #pragma unroll
            for (int s = 0; s < 2; s++)
                #pragma unroll
                for (int r = 0; r < 4; r++) o_acc[mt][s][r] = 0.f;

        const int qmax_w = l0 + w * 32 + 31;   // wave's max q-row
        const int kend   = l0 + 128;

        for (int kb = 0; kb < kend; kb += 64) {
            // hoisted staging loads: registers only until after the sync
            s8v kr[4], vr[4];
            {
                const s8v* ks = (const s8v*)(kbuf + (size_t)(b * L_ + kb + rK) * HD_ + cK);
                const s8v* vs = (const s8v*)(vt + (size_t)(b * HD_ + rV) * L_ + kb + cV);
                #pragma unroll
                for (int u = 0; u < 4; u++) { kr[u] = ks[u]; vr[u] = vs[u]; }
            }
            __syncthreads();   // previous tile fully consumed
            #pragma unroll
            for (int u = 0; u < 4; u++) {
                *(s8v*)&k_lds[rK][cK + u * 8]  = kr[u];
                *(s8v*)&vt_lds[rV][cV + u * 8] = vr[u];
            }
            __syncthreads();   // tile ready

            if (kb <= qmax_w) {
                // ---- S^T = K · Q^T (log2 domain via Q pre-scale) ----
                f4v sacc[4][2];
                #pragma unroll
                for (int jm = 0; jm < 4; jm++)
                    #pragma unroll
                    for (int s = 0; s < 2; s++)
                        #pragma unroll
                        for (int r = 0; r < 4; r++) sacc[jm][s][r] = 0.f;

                __builtin_amdgcn_s_setprio(1);
                #pragma unroll
                for (int kst = 0; kst < 4; kst++) {
                    #pragma unroll
                    for (int jm = 0; jm < 4; jm++) {
                        s8v af = *(const s8v*)&k_lds[jm * 16 + fr][kst * 32 + kg * 8];
                        #pragma unroll
                        for (int s = 0; s < 2; s++)
                            sacc[jm][s] = __builtin_amdgcn_mfma_f32_16x16x32_bf16(
                                af, qf[s][kst], sacc[jm][s], 0, 0, 0);
                    }
                }
                __builtin_amdgcn_s_setprio(0);

                // ---- online softmax per strip ----
                #pragma unroll
                for (int s = 0; s < 2; s++) {
                    const int qrow = l0 + w * 32 + s * 16 + fr;
                    float sv[4][4];
                    if (kb + 63 > l0 + w * 32 + s * 16) {   // diagonal tile: mask
                        #pragma unroll
                        for (int jm = 0; jm < 4; jm++)
                            #pragma unroll
                            for (int r = 0; r < 4; r++) {
                                int key = kb + jm * 16 + kg * 4 + r;
                                sv[jm][r] = (key <= qrow) ? sacc[jm][s][r] : -3.0e38f;
                            }
                    } else {                                 // interior tile
                        #pragma unroll
                        for (int jm = 0; jm < 4; jm++)
                            #pragma unroll
                            for (int r = 0; r < 4; r++) sv[jm][r] = sacc[jm][s][r];
                    }
                    float mj[4];
                    #pragma unroll
                    for (int jm = 0; jm < 4; jm++)
                        mj[jm] = fmaxf(fmaxf(sv[jm][0], sv[jm][1]),
                                       fmaxf(sv[jm][2], sv[jm][3]));
                    float mx = fmaxf(fmaxf(mj[0], mj[1]), fmaxf(mj[2], mj[3]));
                    mx = fmaxf(mx, __shfl_xor(mx, 16));
                    mx = fmaxf(mx, __shfl_xor(mx, 32));

                    // T13 defer-max: only rescale when the max actually grew
                    float mn = m_i[s];
                    if (!__all(mx - mn <= 8.0f)) {
                        float mnew  = fmaxf(mn, mx);
                        float alpha = exp2f(mn - mnew);
                        m_i[s] = mnew;
                        l_i[s] *= alpha;
                        #pragma unroll
                        for (int mt = 0; mt < 8; mt++)
                            #pragma unroll
                            for (int r = 0; r < 4; r++) o_acc[mt][s][r] *= alpha;
                        mn = mnew;
                    }

                    float rs0 = 0.f, rs1 = 0.f;
                    #pragma unroll
                    for (int jm = 0; jm < 4; jm++) {
                        float p0 = exp2f(sv[jm][0] - mn);
                        float p1 = exp2f(sv[jm][1] - mn);
                        float p2 = exp2f(sv[jm][2] - mn);
                        float p3 = exp2f(sv[jm][3] - mn);
                        rs0 += p0 + p2;
                        rs1 += p1 + p3;
                        bf16 pb[4];
                        pb[0] = __float2bfloat16(p0);
                        pb[1] = __float2bfloat16(p1);
                        pb[2] = __float2bfloat16(p2);
                        pb[3] = __float2bfloat16(p3);
                        *(s4v*)&p_lds[w * 32 + s * 16 + fr][jm * 16 + kg * 4] =
                            *(s4v*)&pb[0];
                    }
                    float rsum = rs0 + rs1;
                    rsum += __shfl_xor(rsum, 16);
                    rsum += __shfl_xor(rsum, 32);
                    l_i[s] += rsum;
                }

                // ---- O^T += V^T · P^T ----
                __builtin_amdgcn_s_setprio(1);
                #pragma unroll
                for (int ks2 = 0; ks2 < 2; ks2++) {
                    s8v pf[2];
                    #pragma unroll
                    for (int s = 0; s < 2; s++)
                        pf[s] = *(const s8v*)&p_lds[w * 32 + s * 16 + fr][ks2 * 32 + kg * 8];
                    #pragma unroll
                    for (int mt = 0; mt < 8; mt++) {
                        s8v vf = *(const s8v*)&vt_lds[mt * 16 + fr][ks2 * 32 + kg * 8];
                        #pragma unroll
                        for (int s = 0; s < 2; s++)
                            o_acc[mt][s] = __builtin_amdgcn_mfma_f32_16x16x32_bf16(
                                vf, pf[s], o_acc[mt][s], 0, 0, 0);
                    }
                }
                __builtin_amdgcn_s_setprio(0);
            }
        }

        // ---- epilogue: O^T C-layout -> 4 consecutive hd per lane -> b64 stores
        #pragma unroll
        for (int s = 0; s < 2; s++) {
            float rl = 1.f / l_i[s];
            size_t base = (size_t)(b * L_ + l0 + w * 32 + s * 16 + fr) * D_
                          + h * HD_ + kg * 4;
            #pragma unroll
            for (int mt = 0; mt < 8; mt++) {
                bf16 ob[4];
                #pragma unroll
                for (int r = 0; r < 4; r++)
                    ob[r] = __float2bfloat16(o_acc[mt][s][r] * rl);
                *(s4v*)(o + base + mt * 16) = *(s4v*)&ob[0];
            }
        }
    }
}

// ---------------------------------------------------------------------------
extern "C" void kernel_launch(void* const* d_in, const int* in_sizes, int n_in,
                              void* d_out, int out_size, void* d_ws, size_t ws_size,
                              hipStream_t stream)
{
    const void* x    = d_in[0];
    const void* cosb = d_in[1];
    const void* sinb = d_in[2];
    const void* Wq   = d_in[3];
    const void* Wk   = d_in[4];
    const void* Wv   = d_in[5];
    const void* Wo   = d_in[6];

    const size_t NX   = (size_t)B_ * L_ * D_;     // 16,777,216
    const size_t NW   = (size_t)D_ * D_;          //  4,194,304
    const size_t NWK  = (size_t)HD_ * D_;         //    262,144
    const size_t NKV  = (size_t)B_ * L_ * HD_;    //  1,048,576
    const size_t NOUT = NX + 2 * NKV;             // 18,874,368

    const int xm  = (in_sizes[0] == (int)(NX * 2))  ? 0 : 1;
    const int em  = (in_sizes[1] == (int)((size_t)L_ * 64 * 2)) ? 0 : 1;
    const int wm  = (in_sizes[3] == (int)(NW * 2))  ? 0 : 1;
    const int wkm = (in_sizes[4] == (int)(NWK * 2)) ? 0 : 1;
    const int om  = (out_size    == (int)(NOUT * 2)) ? 0 : 1;

    bf16* qbuf  = (bf16*)d_ws;
    bf16* kvbuf = qbuf  + NX;
    bf16* kbuf  = kvbuf + (size_t)B_ * L_ * 256;
    bf16* vtbuf = kbuf  + NKV;
    bf16* wkvb  = vtbuf + NKV;
    bf16* wwb   = kvbuf;   // 8 MiB scratch spanning kvbuf+kbuf+vtbuf

    const bf16* xb;
    if (xm) {
        cvt_kernel<<<(int)(NX / 8 / 256), 256, 0, stream>>>(x, (bf16*)d_out, (int)(NX / 8), 1);
        xb = (const bf16*)d_out;
    } else {
        xb = (const bf16*)x;
    }

    const bf16* wq;
    if (wm) {
        cvt_kernel<<<(int)(NW / 8 / 256), 256, 0, stream>>>(Wq, wwb, (int)(NW / 8), 1);
        wq = wwb;
    } else {
        wq = (const bf16*)Wq;
    }
    cvt_kernel<<<(int)(NWK / 8 / 256), 256, 0, stream>>>(Wk, wkvb,       (int)(NWK / 8), wkm);
    cvt_kernel<<<(int)(NWK / 8 / 256), 256, 0, stream>>>(Wv, wkvb + NWK, (int)(NWK / 8), wkm);

    // q = x @ Wq^T  (bf16 out into qbuf) — raw; rot+rms fused into attn
    gemm256_kernel<<<dim3(D_ / 256, (B_ * L_) / 256), 512, 0, stream>>>(
        xb, wq, qbuf, 0, 0, D_, D_);
    // [k|v] = x @ [Wk;Wv]^T  (bf16 out, N=256) — skinny N: 128-tile kernel
    gemm_glds_kernel<<<dim3(256 / 128, (B_ * L_) / 128), 256, 0, stream>>>(
        xb, wkvb, kvbuf, 0, 0, 256, D_);

    // k path: rot+rms in place + bf16 copy (kbuf) + new_k output copy
    char* d_out_b = (char*)d_out;
    void* kout2 = d_out_b + NX * (om ? 4 : 2);
    rot_rms_kernel<<<(B_ * L_) / 4, 256, 0, stream>>>(
        kvbuf, 256, 1, 1.0f, cosb, sinb, em, kbuf, kout2, om);

    void* vout2 = d_out_b + (NX + NKV) * (om ? 4 : 2);
    transpose_v_kernel<<<dim3(L_ / 32, HD_ / 32, B_), 256, 0, stream>>>(
        kvbuf, 256, 128, vtbuf, vout2, om);

    // attention: equal-work paired blocks (bx + mirror), grid 512;
    // q rotary+rms fused into the Q-fragment load (vectorized cos/sin)
    attn_kernel<<<dim3(L_ / 256, H_, B_), 256, 0, stream>>>(
        qbuf, kbuf, vtbuf, qbuf, cosb, sinb, em);

    const bf16* wo;
    if (wm) {
        cvt_kernel<<<(int)(NW / 8 / 256), 256, 0, stream>>>(Wo, wwb, (int)(NW / 8), 1);
        wo = wwb;
    } else {
        wo = (const bf16*)Wo;
    }
    // out = attn @ Wo^T  (out-dtype store into d_out) — big N: 4-phase kernel
    gemm256_kernel<<<dim3(D_ / 256, (B_ * L_) / 256), 512, 0, stream>>>(
        qbuf, wo, d_out, 0, om, D_, D_);
}